// Round 11
// baseline (118017.761 us; speedup 1.0000x reference)
//
#include <hip/hip_runtime.h>
#include <cstdint>
#include <cstddef>
#include <math.h>

// Exact Viterbi decode: N=512 states, T=8192, M=50257 tokens.
// R11 = R10 (single-wave forward) with the compile fix: nontemporal
// builtins need NATIVE clang vector types (ext_vector_type), not
// HIP_vector_type classes.
// R10 theory: one wave removes the whole coordination category (0 barriers,
// 0 LDS atomics, all merges in registers); branchless dup-pad pipeline lets
// waitcnt count instead of draining.
// Exactness (same proof chain as R0-R9):
//   SV = {i : v_i >= globalmax - DELTA_W} (argmax always in => n>=1);
//   T  = min_c (achieved col max over SV);
//   row i with fl(v_i + rowmax_i) < T can't win/tie any column (IEEE add
//   monotone); extras {fl(v+rowmax)>=T} \ SV merged inline exactly.
//   Survivor list ASCENDING column index => strict-> merge keeps first
//   index; extras use full tie-break compare. All adds single-rounded,
//   identical op order to reference.

#define NT 512
#define TT 8192
#define MT 50257
#define DELTA_W 0.15f
#define NEG_INF (-3.402823466e38f)

typedef float  f32x4 __attribute__((ext_vector_type(4)));
typedef unsigned u32x4 __attribute__((ext_vector_type(4)));

#define BT_L 32                  // backtrace segment length
#define BT_S (TT / BT_L)         // 256 segments

// ---- workspace layout (bytes) ----
#define WS_LOGPI   0u            // 512 f32
#define WS_VLAST   2048u         // 512 f32
#define WS_BOUND   4096u         // 257 i32
#define WS_ROWMAX  5632u         // 512 f32
#define WS_MAPS    8192u         // 256*512 u16 = 262144
#define WS_LA      270336u       // 512*512 f32 = 1048576 (row-major logA)
#define WS_EMIS    1318912u      // 8192*512 f32 = 16777216 (diag scratch after fwd)
#define WS_BP      18096128u     // 8192*512 u16 = 8388608
#define WS_NEED    26484736u

// Correctly-rounded fp32 logs via fp64 (verified: absmax 0 vs numpy ref).
__global__ void prep_logs(const float* __restrict__ A, const float* __restrict__ Pi,
                          float* __restrict__ lA, float* __restrict__ logPi) {
    int idx = blockIdx.x * blockDim.x + threadIdx.x;
    if (idx < NT * NT) {
        lA[idx] = (float)log((double)A[idx]);
    } else if (idx < NT * NT + NT) {
        int j = idx - NT * NT;
        logPi[j] = (float)log((double)Pi[j]);
    }
}

__global__ void prep_rowmax(const float* __restrict__ lA, float* __restrict__ rowmax) {
    __shared__ float s[4];
    int i = blockIdx.x;
    int t = threadIdx.x;                    // 256 threads
    float m = fmaxf(lA[i * NT + t], lA[i * NT + t + 256]);
    for (int k = 32; k >= 1; k >>= 1) m = fmaxf(m, __shfl_xor(m, k, 64));
    if ((t & 63) == 0) s[t >> 6] = m;
    __syncthreads();
    if (t == 0) {
        float r = fmaxf(fmaxf(s[0], s[1]), fmaxf(s[2], s[3]));
        rowmax[i] = r;
    }
}

__global__ void prep_emis(const float* __restrict__ B, const int* __restrict__ tok,
                          float* __restrict__ emis) {
    int idx = blockIdx.x * blockDim.x + threadIdx.x;   // t*512 + j
    if (idx >= TT * NT) return;
    int t = idx >> 9;
    int j = idx & (NT - 1);
    int tk = tok[t];
    float e;
    if (tk < 0) e = (float)log((double)(1.0f / 512.0f));
    else        e = (float)log((double)B[(size_t)j * MT + tk]);
    emis[idx] = e;
}

// ONE wave, 64 threads. Lane l owns columns/rows l*8+k. No barriers.
__launch_bounds__(64, 1)
__global__ void viterbi_fwd_exact(const float* __restrict__ lA,
                                  const float* __restrict__ rowmax,
                                  const float* emis,          // aliases diag scratch
                                  const float* __restrict__ logPi,
                                  unsigned short* __restrict__ bp,
                                  float* __restrict__ vlast,
                                  float* scratch) {
    __shared__ float2 SV[520];               // survivors (v, idx bits), ascending idx
    __shared__ float2 SVX[520];              // extras (rare), ascending idx

    const int lane = threadIdx.x;            // 0..63
    const int j0   = lane << 3;              // first owned column/row
    const unsigned long long below = (1ull << lane) - 1ull;

    // ---- preamble: warm lA into L2; rmax; v0; emis prefetch ----
    float acc = 0.0f;
    {
        const float4* lAf4 = (const float4*)lA;
        for (int k = lane; k < (NT * NT) / 4; k += 64) acc += lAf4[k].x;
    }
    float rmax[8];
    {
        const float4* rp = (const float4*)(rowmax + j0);
        float4 r0 = rp[0], r1 = rp[1];
        rmax[0]=r0.x; rmax[1]=r0.y; rmax[2]=r0.z; rmax[3]=r0.w;
        rmax[4]=r1.x; rmax[5]=r1.y; rmax[6]=r1.z; rmax[7]=r1.w;
    }
    float v[8];
    {
        const float4* lp = (const float4*)(logPi + j0);
        const float4* ep = (const float4*)(emis + j0);
        float4 l0 = lp[0], l1 = lp[1], e0 = ep[0], e1 = ep[1];
        v[0]=l0.x+e0.x; v[1]=l0.y+e0.y; v[2]=l0.z+e0.z; v[3]=l0.w+e0.w;
        v[4]=l1.x+e1.x; v[5]=l1.y+e1.y; v[6]=l1.z+e1.z; v[7]=l1.w+e1.w;
    }
    if (acc == 1.2345e30f && lane == 63) SVX[0].x = acc;   // keep warm loads alive

    float en[8];                             // emis[t] prefetch
    {
        const f32x4* ep = (const f32x4*)(emis + (size_t)NT + j0);
        f32x4 e0 = __builtin_nontemporal_load(ep);
        f32x4 e1 = __builtin_nontemporal_load(ep + 1);
        en[0]=e0.x; en[1]=e0.y; en[2]=e0.z; en[3]=e0.w;
        en[4]=e1.x; en[5]=e1.y; en[6]=e1.z; en[7]=e1.w;
    }
    long long c0 = clock64();
    long long nAcc = 0;

    for (int t = 1; t < TT; ++t) {
        // ---- emis carry + prefetch(t+1) ----
        float e[8];
        #pragma unroll
        for (int k = 0; k < 8; ++k) e[k] = en[k];
        {
            const int tn = (t + 1 < TT) ? t + 1 : TT - 1;
            const f32x4* ep = (const f32x4*)(emis + (size_t)tn * NT + j0);
            f32x4 e0 = __builtin_nontemporal_load(ep);
            f32x4 e1 = __builtin_nontemporal_load(ep + 1);
            en[0]=e0.x; en[1]=e0.y; en[2]=e0.z; en[3]=e0.w;
            en[4]=e1.x; en[5]=e1.y; en[6]=e1.z; en[7]=e1.w;
        }

        // ---- selection: global max window; compact ascending (lex lane,k) ----
        float lm = v[0];
        #pragma unroll
        for (int k = 1; k < 8; ++k) lm = fmaxf(lm, v[k]);
        float wm = lm;
        #pragma unroll
        for (int d = 1; d <= 32; d <<= 1) wm = fmaxf(wm, __shfl_xor(wm, d, 64));
        const float thr = wm - DELTA_W;      // argmax always selected => n>=1
        bool pr[8];
        unsigned long long mk[8];
        #pragma unroll
        for (int k = 0; k < 8; ++k) { pr[k] = (v[k] >= thr); mk[k] = __ballot(pr[k]); }
        int myBase = 0, n = 0;
        #pragma unroll
        for (int k = 0; k < 8; ++k) {
            myBase += (int)__popcll(mk[k] & below);
            n      += (int)__popcll(mk[k]);
        }
        {
            int pos = myBase;
            #pragma unroll
            for (int k = 0; k < 8; ++k)
                if (pr[k]) { SV[pos] = make_float2(v[k], __int_as_float(j0 + k)); ++pos; }
        }
        nAcc += n;
        const int nm1 = n - 1;

        // ---- scan: groups of 8 rows, branchless double-buffered pipeline ----
        float mv[8]; int bi[8];
        #pragma unroll
        for (int k = 0; k < 8; ++k) { mv[k] = NEG_INF; bi[k] = 0x7fffffff; }
        {
            const float* lAbase = lA + j0;
            float vA[8], vB[8]; int iA[8], iB[8];
            float4 a0[8], a1[8], b0[8], b1[8];
            #pragma unroll
            for (int q = 0; q < 8; ++q) {    // prologue: rows 0..7 (clamp dup-pad)
                int gs = q < n ? q : nm1;
                float2 sv = SV[gs];
                vA[q] = sv.x; iA[q] = __float_as_int(sv.y);
                const float4* rp = (const float4*)(lAbase + ((size_t)(unsigned)iA[q] << 9));
                a0[q] = rp[0]; a1[q] = rp[1];
            }
            int s = 0;
            while (true) {
                #pragma unroll
                for (int q = 0; q < 8; ++q) {     // issue B = rows s+8.. (unconditional)
                    int ss = s + 8 + q; int gs = ss < n ? ss : nm1;
                    float2 sv = SV[gs];
                    vB[q] = sv.x; iB[q] = __float_as_int(sv.y);
                    const float4* rp = (const float4*)(lAbase + ((size_t)(unsigned)iB[q] << 9));
                    b0[q] = rp[0]; b1[q] = rp[1];
                }
                #pragma unroll
                for (int q = 0; q < 8; ++q) {     // merge A (ascending => strict >)
                    float c[8] = {a0[q].x,a0[q].y,a0[q].z,a0[q].w,
                                  a1[q].x,a1[q].y,a1[q].z,a1[q].w};
                    #pragma unroll
                    for (int k = 0; k < 8; ++k) {
                        float sc = vA[q] + c[k];      // single-rounded add == ref
                        if (sc > mv[k]) { mv[k] = sc; bi[k] = iA[q]; }
                    }
                }
                if (s + 8 >= n) break;            // B all dups => skip (idempotent)
                #pragma unroll
                for (int q = 0; q < 8; ++q) {     // issue A' = rows s+16..
                    int ss = s + 16 + q; int gs = ss < n ? ss : nm1;
                    float2 sv = SV[gs];
                    vA[q] = sv.x; iA[q] = __float_as_int(sv.y);
                    const float4* rp = (const float4*)(lAbase + ((size_t)(unsigned)iA[q] << 9));
                    a0[q] = rp[0]; a1[q] = rp[1];
                }
                #pragma unroll
                for (int q = 0; q < 8; ++q) {     // merge B
                    float c[8] = {b0[q].x,b0[q].y,b0[q].z,b0[q].w,
                                  b1[q].x,b1[q].y,b1[q].z,b1[q].w};
                    #pragma unroll
                    for (int k = 0; k < 8; ++k) {
                        float sc = vB[q] + c[k];
                        if (sc > mv[k]) { mv[k] = sc; bi[k] = iB[q]; }
                    }
                }
                if (s + 16 >= n) break;
                s += 16;
            }
        }

        // ---- T (achieved col max over SV, pre-extras); extras inline ----
        float tl = mv[0];
        #pragma unroll
        for (int k = 1; k < 8; ++k) tl = fminf(tl, mv[k]);
        float T = tl;
        #pragma unroll
        for (int d = 1; d <= 32; d <<= 1) T = fminf(T, __shfl_xor(T, d, 64));
        bool px[8];
        unsigned long long mx[8];
        #pragma unroll
        for (int k = 0; k < 8; ++k) {
            px[k] = (v[k] + rmax[k] >= T) && !pr[k];   // fl monotone bound
            mx[k] = __ballot(px[k]);
        }
        int nX = 0;
        #pragma unroll
        for (int k = 0; k < 8; ++k) nX += (int)__popcll(mx[k]);
        if (nX > 0) {                        // small tail (R9: fires often, tiny)
            int xb = 0;
            #pragma unroll
            for (int k = 0; k < 8; ++k) xb += (int)__popcll(mx[k] & below);
            {
                int pos = xb;
                #pragma unroll
                for (int k = 0; k < 8; ++k)
                    if (px[k]) { SVX[pos] = make_float2(v[k], __int_as_float(j0 + k)); ++pos; }
            }
            const float* lAbase = lA + j0;
            const int nXm1 = nX - 1;
            for (int sx = 0; sx < nX; sx += 4) {
                float vE[4]; int iE[4]; float4 e0[4], e1[4];
                #pragma unroll
                for (int q = 0; q < 4; ++q) {
                    int ss = sx + q; int gs = ss < nXm1 ? ss : nXm1;
                    float2 sv = SVX[gs];
                    vE[q] = sv.x; iE[q] = __float_as_int(sv.y);
                    const float4* rp = (const float4*)(lAbase + ((size_t)(unsigned)iE[q] << 9));
                    e0[q] = rp[0]; e1[q] = rp[1];
                }
                #pragma unroll
                for (int q = 0; q < 4; ++q) {     // full tie-break (out of order vs SV)
                    float c[8] = {e0[q].x,e0[q].y,e0[q].z,e0[q].w,
                                  e1[q].x,e1[q].y,e1[q].z,e1[q].w};
                    #pragma unroll
                    for (int k = 0; k < 8; ++k) {
                        float sc = vE[q] + c[k];
                        if (sc > mv[k] || (sc == mv[k] && iE[q] < bi[k])) {
                            mv[k] = sc; bi[k] = iE[q];
                        }
                    }
                }
            }
        }

        // ---- finalize: vn, packed bp store ----
        #pragma unroll
        for (int k = 0; k < 8; ++k) v[k] = mv[k] + e[k];   // single-rounded == ref
        {
            u32x4 pk;
            pk.x = ((unsigned)bi[0] & 0xFFFFu) | ((unsigned)bi[1] << 16);
            pk.y = ((unsigned)bi[2] & 0xFFFFu) | ((unsigned)bi[3] << 16);
            pk.z = ((unsigned)bi[4] & 0xFFFFu) | ((unsigned)bi[5] << 16);
            pk.w = ((unsigned)bi[6] & 0xFFFFu) | ((unsigned)bi[7] << 16);
            __builtin_nontemporal_store(pk, (u32x4*)(bp + (size_t)t * NT + j0));
        }
        if (t == TT - 1) {
            float4* vp = (float4*)(vlast + j0);
            vp[0] = make_float4(v[0], v[1], v[2], v[3]);
            vp[1] = make_float4(v[4], v[5], v[6], v[7]);
        }
    }

    // ---- diagnostics: P = min(255,cyc>>8)*16 + min(15, mean_n>>4) ----
    // decode: P = 2*(WRITE_KB - 8193); cb = P>>4 (256-cy buckets); nb = P&15.
    {
        long long cyc = (clock64() - c0) / (long long)(TT - 1);
        int cb = (int)(cyc >> 8); if (cb > 255) cb = 255; if (cb < 0) cb = 0;
        int mn = (int)(nAcc / (long long)(TT - 1));
        int nb = mn >> 4; if (nb > 15) nb = 15;
        const int P = cb * 16 + nb;
        for (int pg = 0; pg < P; ++pg) {
            unsigned long long val = ((unsigned long long)pg << 32) | (unsigned)lane;
            __builtin_nontemporal_store(val,
                (unsigned long long*)((char*)scratch + (size_t)pg * 4096) + lane);
        }
    }
}

// ---- backtrace: per-segment map composition (verified exact) ----
__launch_bounds__(NT, 1)
__global__ void bt_maps(const unsigned short* __restrict__ bp,
                        unsigned short* __restrict__ maps) {
    __shared__ unsigned short bps[BT_L * NT];
    const int s = blockIdx.x;
    const int tlo = BT_L * s + 1;
    int thi = BT_L * (s + 1); if (thi > TT - 1) thi = TT - 1;
    const int nt = thi - tlo + 1;
    for (int k = threadIdx.x; k < nt * NT; k += NT)
        bps[k] = bp[(size_t)tlo * NT + k];
    __syncthreads();
    int cur = threadIdx.x;
    for (int r = nt - 1; r >= 0; --r) cur = bps[r * NT + cur];
    maps[s * NT + threadIdx.x] = (unsigned short)cur;
}

__launch_bounds__(NT, 1)
__global__ void bt_bound(const float* __restrict__ vlast,
                         const unsigned short* __restrict__ maps,
                         int* __restrict__ bound) {
    __shared__ float sv[NT];
    __shared__ int   si[NT];
    int j = threadIdx.x;
    sv[j] = vlast[j]; si[j] = j;
    __syncthreads();
    for (int off = NT / 2; off > 0; off >>= 1) {
        if (j < off) {
            float v2 = sv[j + off]; int i2 = si[j + off];
            if (v2 > sv[j] || (v2 == sv[j] && i2 < si[j])) { sv[j] = v2; si[j] = i2; }
        }
        __syncthreads();
    }
    if (j == 0) {
        int cur = si[0];
        bound[BT_S] = cur;
        for (int s = BT_S - 1; s >= 0; --s) {
            cur = maps[s * NT + cur];
            bound[s] = cur;
        }
    }
}

__launch_bounds__(NT, 1)
__global__ void bt_path(const unsigned short* __restrict__ bp,
                        const int* __restrict__ bound,
                        int* __restrict__ path) {
    __shared__ unsigned short bps[BT_L * NT];
    const int s = blockIdx.x;
    const int tlo = BT_L * s + 1;
    int thi = BT_L * (s + 1); if (thi > TT - 1) thi = TT - 1;
    const int nt = thi - tlo + 1;
    for (int k = threadIdx.x; k < nt * NT; k += NT)
        bps[k] = bp[(size_t)tlo * NT + k];
    __syncthreads();
    if (threadIdx.x == 0) {
        int cur = bound[s + 1];
        if (s == BT_S - 1) path[TT - 1] = cur;
        for (int r = nt - 1; r >= 0; --r) {
            cur = bps[r * NT + cur];
            path[tlo - 1 + r] = cur;
        }
    }
}

extern "C" void kernel_launch(void* const* d_in, const int* in_sizes, int n_in,
                              void* d_out, int out_size, void* d_ws, size_t ws_size,
                              hipStream_t stream) {
    const int*   tok = (const int*)d_in[0];
    const float* A   = (const float*)d_in[1];
    const float* B   = (const float*)d_in[2];
    const float* Pi  = (const float*)d_in[3];
    int* path = (int*)d_out;
    char* ws = (char*)d_ws;
    if (ws_size < (size_t)WS_NEED) return;

    float* logPi          = (float*)(ws + WS_LOGPI);
    float* vlast          = (float*)(ws + WS_VLAST);
    int*   bound          = (int*)(ws + WS_BOUND);
    float* rowmax         = (float*)(ws + WS_ROWMAX);
    unsigned short* maps  = (unsigned short*)(ws + WS_MAPS);
    float* lA             = (float*)(ws + WS_LA);
    float* emis           = (float*)(ws + WS_EMIS);
    unsigned short* bpp   = (unsigned short*)(ws + WS_BP);

    prep_logs  <<<(NT * NT + NT + 255) / 256, 256, 0, stream>>>(A, Pi, lA, logPi);
    prep_emis  <<<(TT * NT) / 256,            256, 0, stream>>>(B, tok, emis);
    prep_rowmax<<<NT, 256, 0, stream>>>(lA, rowmax);
    viterbi_fwd_exact<<<1, 64, 0, stream>>>(lA, rowmax, emis, logPi, bpp, vlast,
                                            emis /*diag scratch*/);
    bt_maps  <<<BT_S, NT, 0, stream>>>(bpp, maps);
    bt_bound <<<1,    NT, 0, stream>>>(vlast, maps, bound);
    bt_path  <<<BT_S, NT, 0, stream>>>(bpp, bound, path);
}